// Round 1
// baseline (313.781 us; speedup 1.0000x reference)
//
#include <hip/hip_runtime.h>

// out[b,s,d] = X[b,s,d] * W[reward[b,s]][0] + Y[b,s,d] * W[reward[b,s]][1]
// B=4, S=4096, D=2048 (f32). Memory-bound: ~402 MB HBM traffic -> ~64us floor.

#define D_PER_ROW   2048
#define F4_PER_ROW  (D_PER_ROW / 4)   // 512
#define LOG2_F4ROW  9

__global__ __launch_bounds__(256) void
mla_kernel(const float* __restrict__ X,
           const float* __restrict__ Y,
           const int*   __restrict__ reward,
           const float* __restrict__ W,
           float*       __restrict__ out,
           long long n4)
{
    // Hoist the 2x2 weight matrix into registers (uniform, cached).
    const float w00 = W[0], w01 = W[1];  // row 0: [alpha0, 1-alpha0]
    const float w10 = W[2], w11 = W[3];  // row 1: [alpha1, 1-alpha1]

    long long i      = (long long)blockIdx.x * blockDim.x + threadIdx.x;
    long long stride = (long long)gridDim.x * blockDim.x;

    const float4* __restrict__ X4 = reinterpret_cast<const float4*>(X);
    const float4* __restrict__ Y4 = reinterpret_cast<const float4*>(Y);
    float4*       __restrict__ O4 = reinterpret_cast<float4*>(out);

    for (; i < n4; i += stride) {
        const long long row = i >> LOG2_F4ROW;     // which (b,s) row
        const int idx = reward[row];               // 0 or 1 (L1/L2 resident)
        const float a = idx ? w10 : w00;           // v_cndmask, no divergence
        const float b = idx ? w11 : w01;

        const float4 x = X4[i];
        const float4 y = Y4[i];
        float4 o;
        o.x = fmaf(x.x, a, y.x * b);
        o.y = fmaf(x.y, a, y.y * b);
        o.z = fmaf(x.z, a, y.z * b);
        o.w = fmaf(x.w, a, y.w * b);
        O4[i] = o;
    }
}

extern "C" void kernel_launch(void* const* d_in, const int* in_sizes, int n_in,
                              void* d_out, int out_size, void* d_ws, size_t ws_size,
                              hipStream_t stream)
{
    // setup_inputs() order: X, Y, reward, W
    const float* X      = (const float*)d_in[0];
    const float* Y      = (const float*)d_in[1];
    const int*   reward = (const int*)  d_in[2];   // harness passes integers as int32
    const float* W      = (const float*)d_in[3];
    float*       out    = (float*)d_out;

    const long long n  = (long long)out_size;      // B*S*D = 33,554,432
    const long long n4 = n >> 2;                   // float4 count

    const int block = 256;
    const int grid  = 2048;                        // ~8 blocks/CU, grid-stride the rest

    mla_kernel<<<grid, block, 0, stream>>>(X, Y, reward, W, out, n4);
}